// Round 9
// baseline (140.575 us; speedup 1.0000x reference)
//
#include <hip/hip_runtime.h>
#include <hip/hip_bf16.h>
#include <stdint.h>

typedef __bf16 bf16_t;
typedef __bf16 bf16x8 __attribute__((ext_vector_type(8)));
typedef __bf16 bf16x4 __attribute__((ext_vector_type(4)));
typedef float  f32x4  __attribute__((ext_vector_type(4)));

#define DIM   1024
#define BATCH 8
#define NTOK  (BATCH * DIM)   /* 8192 */
#define SCALE 0.03125f        /* 1/sqrt(1024) */

// ---------------- f32 -> bf16 convert (vectorized) ----------------
__global__ void k_cvt(const float* __restrict__ in, bf16_t* __restrict__ out, int n4) {
    int i = blockIdx.x * blockDim.x + threadIdx.x;
    if (i < n4) {
        const float4 v = reinterpret_cast<const float4*>(in)[i];
        bf16x4 o;
        o.x = (bf16_t)v.x; o.y = (bf16_t)v.y; o.z = (bf16_t)v.z; o.w = (bf16_t)v.w;
        reinterpret_cast<bf16x4*>(out)[i] = o;
    }
}

// ------------- W_eff^T[e][d] = bf16( sum_n w[n][d][e] ) -------------
__global__ void k_weff(const float* __restrict__ w, bf16_t* __restrict__ wt) {
    __shared__ float tile[32][33];
    const int tx = threadIdx.x & 31;
    const int ty = threadIdx.x >> 5;
    const int d0 = blockIdx.x * 32;
    const int e0 = blockIdx.y * 32;
#pragma unroll
    for (int r = 0; r < 4; ++r) {
        const int d = d0 + r * 8 + ty;
        const int e = e0 + tx;
        tile[r * 8 + ty][tx] =
            w[d * 1024 + e] + w[1048576 + d * 1024 + e] + w[2097152 + d * 1024 + e];
    }
    __syncthreads();
#pragma unroll
    for (int r = 0; r < 4; ++r) {
        const int e = e0 + r * 8 + ty;
        const int d = d0 + tx;
        wt[e * 1024 + d] = (bf16_t)tile[tx][r * 8 + ty];
    }
}

// ------------- WqT[d][e] = bf16( Wqkv[e*1024 + d] ) -------------
__global__ void k_trans(const float* __restrict__ in, bf16_t* __restrict__ out) {
    __shared__ float tile[32][33];
    const int tx = threadIdx.x & 31;
    const int ty = threadIdx.x >> 5;
    const int e0 = blockIdx.x * 32;
    const int d0 = blockIdx.y * 32;
#pragma unroll
    for (int r = 0; r < 4; ++r)
        tile[r * 8 + ty][tx] = in[(long)(e0 + r * 8 + ty) * 1024 + d0 + tx];
    __syncthreads();
#pragma unroll
    for (int r = 0; r < 4; ++r)
        out[(long)(d0 + r * 8 + ty) * 1024 + e0 + tx] = (bf16_t)tile[tx][r * 8 + ty];
}

// ------------- bqw[n] = sum_d bq[d] * WeffT[n][d]  (wave-parallel) -------------
__global__ void k_bqw(const float* __restrict__ bq, const bf16_t* __restrict__ wtb,
                      float* __restrict__ bqw) {
    const int wave = threadIdx.x >> 6, lane = threadIdx.x & 63;
    const int n = blockIdx.x * 4 + wave;
    const bf16_t* row = wtb + (long)n * 1024;
    float s = 0.f;
#pragma unroll
    for (int c = 0; c < 2; ++c) {
        const int d0 = (lane + c * 64) * 8;
        const bf16x8 v = *reinterpret_cast<const bf16x8*>(row + d0);
#pragma unroll
        for (int e = 0; e < 8; ++e) s += bq[d0 + e] * (float)v[e];
    }
#pragma unroll
    for (int off = 32; off; off >>= 1) s += __shfl_down(s, off);
    if (lane == 0) bqw[n] = s;
}

// -------- B' split-K GEMM: oAt (+)= partial A@B^T (proven R8) ----
__global__ __launch_bounds__(256)
void k_sk(const bf16_t* __restrict__ A, const bf16_t* __restrict__ B,
          float* __restrict__ oAt)
{
    __shared__ __align__(16) bf16_t As[128 * 32];
    __shared__ __align__(16) bf16_t Bs[128 * 32];

    const int tid  = threadIdx.x;
    const int wave = tid >> 6;
    const int lane = tid & 63;
    const int wr = wave >> 1, wc = wave & 1;
    const int lhi = lane >> 4, llo = lane & 15;

    const int bm = blockIdx.x * 128;
    const int bn = blockIdx.y * 128;
    const int kb = blockIdx.z * 256;

    f32x4 acc[4][4];
    const f32x4 fz = {0.f, 0.f, 0.f, 0.f};
#pragma unroll
    for (int i = 0; i < 4; ++i)
#pragma unroll
        for (int j = 0; j < 4; ++j) acc[i][j] = fz;

    for (int k0 = 0; k0 < 256; k0 += 32) {
#pragma unroll
        for (int i = 0; i < 2; ++i) {
            const int c  = wave * 128 + i * 64 + lane;
            const int r  = c >> 2;
            const int cc = (c & 3) << 3;
            const long ga = (long)(bm + r) * 1024 + kb + k0 + cc;
            const long gb = (long)(bn + r) * 1024 + kb + k0 + cc;
            const int lbase = (wave * 128 + i * 64) << 3;
            __builtin_amdgcn_global_load_lds(
                (const __attribute__((address_space(1))) uint32_t*)(A + ga),
                (__attribute__((address_space(3))) uint32_t*)(&As[lbase]), 16, 0, 0);
            __builtin_amdgcn_global_load_lds(
                (const __attribute__((address_space(1))) uint32_t*)(B + gb),
                (__attribute__((address_space(3))) uint32_t*)(&Bs[lbase]), 16, 0, 0);
        }
        __syncthreads();

        bf16x8 af[4], bfr[4];
#pragma unroll
        for (int mi = 0; mi < 4; ++mi)
            af[mi] = *reinterpret_cast<const bf16x8*>(&As[(wr * 64 + mi * 16 + llo) * 32 + lhi * 8]);
#pragma unroll
        for (int ni = 0; ni < 4; ++ni)
            bfr[ni] = *reinterpret_cast<const bf16x8*>(&Bs[(wc * 64 + ni * 16 + llo) * 32 + lhi * 8]);
#pragma unroll
        for (int mi = 0; mi < 4; ++mi)
#pragma unroll
            for (int ni = 0; ni < 4; ++ni)
                acc[mi][ni] = __builtin_amdgcn_mfma_f32_16x16x32_bf16(af[mi], bfr[ni], acc[mi][ni], 0, 0, 0);
        __syncthreads();
    }

#pragma unroll
    for (int mi = 0; mi < 4; ++mi) {
        const int r0 = bm + wr * 64 + mi * 16 + lhi * 4;
#pragma unroll
        for (int ni = 0; ni < 4; ++ni) {
            const int cg = bn + wc * 64 + ni * 16 + llo;
            const f32x4 v = acc[mi][ni];
#pragma unroll
            for (int j = 0; j < 4; ++j)
                atomicAdd(&oAt[(long)(r0 + j) * 1024 + cg], v[j]);
        }
    }
}

// ============ BM=256 x BN_, BK=64, dbuf, 4-phase per K-tile pipeline ============
// C[m][n] = sum_k A[m][k]*B[n][k], K=1024 (NTT=16 tiles of BK=64).
// 8 waves (2M x 4N): per-wave 128 x (BN_/4); acc[8][NF].
// Staging granularity: PASS = 64 rows x 64k x 2B = 8KB = 512 thr x 16B gload.
//   MODE1 (BN_=192): 7 passes/tile (A0-3, B0-2). MODE2 (BN_=128): 6 (A0-3, B0-1).
// Phase (mh, s): { reads: af[mh*4..+3]_s (4) [+ bf_s (NF) when mh==0];
//   stage passes (see ledger); barrier; lgkmcnt(0); setprio1; 4*NF MFMA;
//   setprio0; [vmcnt(4) gate at ph0 & ph3]; barrier }.
// Ledger (verified): A-pass(mh0 rows) freed end-ph2, (mh1) end-ph3; B freed
//   end-ph2. Stage at tile u: ph0:{B2,A0}(u+1) ph1:{A2,A1}(u+1) ph2:{A3}(u+1)
//   ph3:{B0,B1}(u+2). Gate end-ph0: newest-4 outstanding = passes not yet
//   needed, forces A3(u) & older landed (needed by ph1). Gate end-ph3: forces
//   A2(u+1) & older (needed by next ph0). Counted, never 0 mid-loop.
// Swizzle (R8-proven): row=128B of 8 chunks; phys chunk = logical ^ (row&7);
//   staged linearly from inverse-swizzled global source.
#define GLOAD(SRC, DST) __builtin_amdgcn_global_load_lds( \
    (const __attribute__((address_space(1))) uint32_t*)(SRC), \
    (__attribute__((address_space(3))) uint32_t*)(DST), 16, 0, 0)

template<int MODE>
__global__ __launch_bounds__(512, 2)
void k8(const bf16_t* __restrict__ A, const bf16_t* __restrict__ Bp,
        const float* __restrict__ bias_q, const float* __restrict__ bias_kv,
        bf16_t* __restrict__ oQW, bf16_t* __restrict__ oK,
        float* __restrict__ oV, float* __restrict__ oF)
{
    constexpr int NF   = (MODE == 1) ? 3 : 2;       // n-frags per wave
    constexpr int BN   = NF * 64;                   // 192 / 128
    constexpr int NB   = BN / 64;                   // B passes: 3 / 2
    constexpr int NP   = 4 + NB;                    // total passes
    constexpr int SLOT = 32768 + BN * 128;          // A 32KB + B
    constexpr int NTT  = 16;
    __shared__ __align__(16) unsigned char slds[2 * SLOT];

    const int tid  = threadIdx.x;
    const int wave = tid >> 6, lane = tid & 63;
    const int wm = wave >> 2, wn = wave & 3;
    const int llo = lane & 15, lhi = lane >> 4;

    // ---- grid decode ----
    int bmA, bnB, bnOut;            // A-row base, B-row base, out-col base
    if (MODE == 1) {
        const int xcd = (int)blockIdx.x & 7, idx = (int)blockIdx.x >> 3;
        bmA  = (xcd * 4 + (idx >> 4)) * 256;      // m-grouped per XCD
        bnB  = (idx & 15) * 192;
        bnOut = bnB;
    } else {
        const int xcd = (int)blockIdx.x & 7, idx = (int)blockIdx.x >> 3;
        bmA  = xcd * 1024 + (idx >> 3) * 256;     // XCD = batch
        bnOut = (idx & 7) * 128;
        bnB  = xcd * 1024 + bnOut;
    }

    // ---- per-thread pass sources (inverse-swizzled) + linear LDS dests ----
    const int prow = tid >> 3;                     // 0..63 row within pass
    const int uch  = (tid & 7) ^ (prow & 7);       // inverse-swizzled chunk
    const bf16_t* sp[NP]; int dst[NP];
#pragma unroll
    for (int j = 0; j < 4; ++j) {                  // A passes
        const int row = j * 64 + prow;
        sp[j]  = A + (long)(bmA + row) * 1024 + uch * 8;
        dst[j] = row * 128 + (tid & 7) * 16;
    }
#pragma unroll
    for (int j = 0; j < NB; ++j) {                 // B passes
        const int row = j * 64 + prow;
        sp[4 + j]  = Bp + (long)(bnB + row) * 1024 + uch * 8;
        dst[4 + j] = 32768 + row * 128 + (tid & 7) * 16;
    }

#define STG(TT, J) GLOAD(sp[J] + (long)(TT) * 64, slds + ((TT) & 1) * SLOT + dst[J])

    f32x4 acc[8][NF];
    const f32x4 fz = {0.f, 0.f, 0.f, 0.f};
#pragma unroll
    for (int i = 0; i < 8; ++i)
#pragma unroll
        for (int j = 0; j < NF; ++j) acc[i][j] = fz;

    // ---- prologue: tile0 fully, B0,B1 of tile1; force tile0 landed ----
#pragma unroll
    for (int j = 0; j < NP; ++j) STG(0, j);
    STG(1, 4); STG(1, 5);
    asm volatile("s_waitcnt vmcnt(2)" ::: "memory");
    __builtin_amdgcn_s_barrier();

    for (int u = 0; u < NTT; ++u) {
        const unsigned char* rb = slds + (u & 1) * SLOT;
        bf16x8 af[4], bfv[NF];

        // ===================== ph0 (mh0, s0) =====================
#pragma unroll
        for (int mi = 0; mi < 4; ++mi) {
            const int r = wm * 128 + mi * 16 + llo;
            af[mi] = *reinterpret_cast<const bf16x8*>(rb + r * 128 + ((lhi ^ (r & 7)) << 4));
        }
#pragma unroll
        for (int ni = 0; ni < NF; ++ni) {
            const int r = wn * (NF * 16) + ni * 16 + llo;
            bfv[ni] = *reinterpret_cast<const bf16x8*>(rb + 32768 + r * 128 + ((lhi ^ (r & 7)) << 4));
        }
        if (u + 1 < NTT) {
            if (MODE == 1) STG(u + 1, 6);
            else           STG(u + 1, 2);
            STG(u + 1, 0);
        }
        __builtin_amdgcn_s_barrier();
        asm volatile("s_waitcnt lgkmcnt(0)" ::: "memory");
        __builtin_amdgcn_s_setprio(1);
#pragma unroll
        for (int mi = 0; mi < 4; ++mi)
#pragma unroll
            for (int ni = 0; ni < NF; ++ni)
                acc[mi][ni] = __builtin_amdgcn_mfma_f32_16x16x32_bf16(af[mi], bfv[ni], acc[mi][ni], 0, 0, 0);
        __builtin_amdgcn_s_setprio(0);
        asm volatile("s_waitcnt vmcnt(4)" ::: "memory");   // gate: A1,A3(u) landed
        __builtin_amdgcn_s_barrier();

        // ===================== ph1 (mh1, s0) =====================
#pragma unroll
        for (int mi = 0; mi < 4; ++mi) {
            const int r = wm * 128 + (mi + 4) * 16 + llo;
            af[mi] = *reinterpret_cast<const bf16x8*>(rb + r * 128 + ((lhi ^ (r & 7)) << 4));
        }
        if (u + 1 < NTT) {
            if (MODE == 1) { STG(u + 1, 2); STG(u + 1, 1); }
            else           STG(u + 1, 1);
        }
        __builtin_amdgcn_s_barrier();
        asm volatile("s_waitcnt lgkmcnt(0)" ::: "memory");
        __builtin_amdgcn_s_setprio(1);
#pragma unroll
        for (int mi = 0; mi < 4; ++mi)
#pragma unroll
            for (int ni = 0; ni < NF; ++ni)
                acc[mi + 4][ni] = __builtin_amdgcn_mfma_f32_16x16x32_bf16(af[mi], bfv[ni], acc[mi + 4][ni], 0, 0, 0);
        __builtin_amdgcn_s_setprio(0);
        __builtin_amdgcn_s_barrier();

        // ===================== ph2 (mh0, s1) =====================
#pragma unroll
        for (int mi = 0; mi < 4; ++mi) {
            const int r = wm * 128 + mi * 16 + llo;
            af[mi] = *reinterpret_cast<const bf16x8*>(rb + r * 128 + (((4 | lhi) ^ (r & 7)) << 4));
        }
#pragma unroll
        for (int ni = 0; ni < NF; ++ni) {
            const int r = wn * (NF * 16) + ni * 16 + llo;
            bfv[ni] = *reinterpret_cast<const bf16x8*>(rb + 32768 + r * 128 + (((4 | lhi) ^ (r & 7)) << 4));
        }
        if (u + 1 < NTT) STG(u + 1, 3);
        __builtin_amdgcn_s_barrier();
        asm volatile("s_waitcnt lgkmcnt(0)" ::: "memory");
        __builtin_amdgcn_s_setprio(1);
#pragma unroll
        for (int mi = 0; mi < 4; ++mi)
#pragma unroll
            for (int ni = 0; ni < NF; ++ni)
                acc[mi][ni] = __builtin_amdgcn_mfma_f32_16x16x32_bf16(af[mi], bfv[ni], acc[mi][ni], 0, 0, 0);
        __builtin_amdgcn_s_setprio(0);
        __builtin_amdgcn_s_barrier();

        // ===================== ph3 (mh1, s1) =====================
#pragma unroll
        for (int mi = 0; mi < 4; ++mi) {
            const int r = wm * 128 + (mi + 4) * 16 + llo;
            af[mi] = *reinterpret_cast<const bf16x8*>(rb + r * 128 + (((4 | lhi) ^ (r & 7)) << 4));
        }
        if (u + 2 < NTT) { STG(u + 2, 4); STG(u + 2, 5); }
        __builtin_amdgcn_s_barrier();
        asm volatile("s_waitcnt lgkmcnt(0)" ::: "memory");
        __builtin_amdgcn_s_setprio(1);
#pragma unroll
        for (int mi = 0; mi < 4; ++mi)
#pragma unroll
            for (int ni = 0; ni < NF; ++ni)
                acc[mi + 4][ni] = __builtin_amdgcn_mfma_f32_16x16x32_bf16(af[mi], bfv[ni], acc[mi + 4][ni], 0, 0, 0);
        __builtin_amdgcn_s_setprio(0);
        asm volatile("s_waitcnt vmcnt(4)" ::: "memory");   // gate: A2(u+1) & older landed
        __builtin_amdgcn_s_barrier();
    }

    // ---------------- epilogue ----------------
#pragma unroll
    for (int mi = 0; mi < 8; ++mi) {
        const long r0 = bmA + wm * 128 + mi * 16 + lhi * 4;
#pragma unroll
        for (int ni = 0; ni < NF; ++ni) {
            const int cg = bnOut + wn * (NF * 16) + ni * 16 + llo;
            const f32x4 v = acc[mi][ni];
            if (MODE == 1) {
                const int sec = cg >> 10;
                const int c1  = cg & 1023;
                const float bb = (sec == 0) ? bias_q[cg] : bias_kv[cg];
#pragma unroll
                for (int j = 0; j < 4; ++j) {
                    const long idx = (r0 + j) * 1024 + c1;
                    const float val = v[j] + bb;
                    if (sec == 0)      oQW[idx] = (bf16_t)val;
                    else if (sec == 1) oK[idx] = (bf16_t)val;
                    else               oV[idx] = val;
                }
            } else {
#pragma unroll
                for (int j = 0; j < 4; ++j) {
                    const long idx = (r0 + j) * 1024 + cg;
                    oF[idx] = oF[idx] + SCALE * v[j];
                }
            }
        }
    }
}
#undef STG
#undef GLOAD

extern "C" void kernel_launch(void* const* d_in, const int* in_sizes, int n_in,
                              void* d_out, int out_size, void* d_ws, size_t ws_size,
                              hipStream_t stream) {
    const float* x    = (const float*)d_in[0];
    const float* Wqkv = (const float*)d_in[1];
    const float* bqkv = (const float*)d_in[2];
    const float* w    = (const float*)d_in[3];
    float* out = (float*)d_out;

    // workspace layout (54 MiB + 64 KiB)
    char* ws = (char*)d_ws;
    bf16_t* xb   = (bf16_t*)(ws);                          // 16 MiB
    bf16_t* wbig = (bf16_t*)(ws + (16l << 20));            // 6 MiB: [B'; Wk; Wv]
    float*  bqw  = (float*) (ws + (22l << 20));            // 4 KiB (64 KiB reserved)
    bf16_t* kb   = (bf16_t*)(ws + (22l << 20) + 65536);    // 16 MiB
    bf16_t* qwb  = (bf16_t*)(ws + (38l << 20) + 65536);    // 16 MiB (region reused)
    bf16_t* wtb  = qwb;                    // 2 MiB WeffT   (dead before qwb written)
    bf16_t* wqt  = qwb + 1048576;          // 2 MiB WqT     (dead before qwb written)
    float*  bp32 = (float*)(qwb + 2097152);// 4 MiB f32 B'  (dead before qwb written)
    if (ws_size < (size_t)(54l << 20) + 65536) return;

    // preamble
    k_cvt  <<<8192, 256, 0, stream>>>(x, xb, 2097152);
    k_cvt  <<<2048, 256, 0, stream>>>(Wqkv + 1048576, wbig + 1048576, 524288);
    k_weff <<<dim3(32, 32), 256, 0, stream>>>(w, wtb);
    k_trans<<<dim3(32, 32), 256, 0, stream>>>(Wqkv, wqt);
    k_bqw  <<<256, 256, 0, stream>>>(bqkv, wtb, bqw);

    // B' = WeffT @ WqT^T  (split-K=4, f32 atomics), then cvt to bf16
    hipMemsetAsync(bp32, 0, 4194304, stream);
    k_sk <<<dim3(8, 8, 4), 256, 0, stream>>>(wtb, wqt, bp32);
    k_cvt<<<1024, 256, 0, stream>>>(bp32, wbig, 262144);

    // fused projection: [qw | k | v] = x @ wbig^T + bias; 512 blocks = 2 exact rounds
    k8<1><<<512, 512, 0, stream>>>(xb, wbig, bqw, bqkv, qwb, kb, out, nullptr);

    // scores: out += SCALE * qw @ k^T; 256 blocks = 1 round, XCD = batch
    k8<2><<<256, 512, 0, stream>>>(qwb, kb, nullptr, nullptr,
                                   nullptr, nullptr, nullptr, out);
}

// Round 10
// 116.955 us; speedup vs baseline: 1.2020x; 1.2020x over previous
//
#include <hip/hip_runtime.h>
#include <hip/hip_bf16.h>
#include <stdint.h>

typedef __bf16 bf16_t;
typedef __bf16 bf16x8 __attribute__((ext_vector_type(8)));
typedef __bf16 bf16x4 __attribute__((ext_vector_type(4)));
typedef float  f32x4  __attribute__((ext_vector_type(4)));

#define DIM   1024
#define BATCH 8
#define NTOK  (BATCH * DIM)   /* 8192 */
#define SCALE 0.03125f        /* 1/sqrt(1024) */

// ---------------- f32 -> bf16 convert (vectorized) ----------------
__global__ void k_cvt(const float* __restrict__ in, bf16_t* __restrict__ out, int n4) {
    int i = blockIdx.x * blockDim.x + threadIdx.x;
    if (i < n4) {
        const float4 v = reinterpret_cast<const float4*>(in)[i];
        bf16x4 o;
        o.x = (bf16_t)v.x; o.y = (bf16_t)v.y; o.z = (bf16_t)v.z; o.w = (bf16_t)v.w;
        reinterpret_cast<bf16x4*>(out)[i] = o;
    }
}

// ============== K1: fused preamble (verbatim role bodies, index remap) ==============
// blocks [0,8192):      xb = bf16(x)                  (2097152 f32x4)
// blocks [8192,10240):  wbig[1M..] = bf16(Wqkv[1M..]) (524288 f32x4)
// blocks [10240,11264): wtb = WeffT (transpose-sum of w), 32x32 tiles
// blocks [11264,12288): wqt = WqT (transpose of Wqkv rows [0,1024)), 32x32 tiles
// blocks [12288,13312): bp32 = 0                      (262144 f32x4)
__global__ __launch_bounds__(256)
void k_prep(const float* __restrict__ x, const float* __restrict__ Wqkv,
            const float* __restrict__ w,
            bf16_t* __restrict__ xb, bf16_t* __restrict__ wbig,
            bf16_t* __restrict__ wtb, bf16_t* __restrict__ wqt,
            float* __restrict__ bp32)
{
    __shared__ float tile[32][33];
    const int b = blockIdx.x;
    if (b < 8192) {
        const int i = b * 256 + threadIdx.x;
        const float4 v = reinterpret_cast<const float4*>(x)[i];
        bf16x4 o;
        o.x = (bf16_t)v.x; o.y = (bf16_t)v.y; o.z = (bf16_t)v.z; o.w = (bf16_t)v.w;
        reinterpret_cast<bf16x4*>(xb)[i] = o;
    } else if (b < 10240) {
        const int i = (b - 8192) * 256 + threadIdx.x;
        const float4 v = reinterpret_cast<const float4*>(Wqkv + 1048576)[i];
        bf16x4 o;
        o.x = (bf16_t)v.x; o.y = (bf16_t)v.y; o.z = (bf16_t)v.z; o.w = (bf16_t)v.w;
        reinterpret_cast<bf16x4*>(wbig + 1048576)[i] = o;
    } else if (b < 11264) {
        const int t  = b - 10240;
        const int tx = threadIdx.x & 31, ty = threadIdx.x >> 5;
        const int d0 = (t & 31) * 32, e0 = (t >> 5) * 32;
#pragma unroll
        for (int r = 0; r < 4; ++r) {
            const int d = d0 + r * 8 + ty;
            const int e = e0 + tx;
            tile[r * 8 + ty][tx] =
                w[d * 1024 + e] + w[1048576 + d * 1024 + e] + w[2097152 + d * 1024 + e];
        }
        __syncthreads();
#pragma unroll
        for (int r = 0; r < 4; ++r) {
            const int e = e0 + r * 8 + ty;
            const int d = d0 + tx;
            wtb[e * 1024 + d] = (bf16_t)tile[tx][r * 8 + ty];
        }
    } else if (b < 12288) {
        const int t  = b - 11264;
        const int tx = threadIdx.x & 31, ty = threadIdx.x >> 5;
        const int e0 = (t & 31) * 32, d0 = (t >> 5) * 32;
#pragma unroll
        for (int r = 0; r < 4; ++r)
            tile[r * 8 + ty][tx] = Wqkv[(long)(e0 + r * 8 + ty) * 1024 + d0 + tx];
        __syncthreads();
#pragma unroll
        for (int r = 0; r < 4; ++r)
            wqt[(long)(d0 + r * 8 + ty) * 1024 + e0 + tx] = (bf16_t)tile[tx][r * 8 + ty];
    } else {
        const int i = (b - 12288) * 256 + threadIdx.x;
        const f32x4 z = {0.f, 0.f, 0.f, 0.f};
        reinterpret_cast<f32x4*>(bp32)[i] = z;
    }
}

// ====== K2: bqw (wave-parallel dot) ∪ B' split-K GEMM (f32 atomicAdd) ======
// blocks [0,256):   bqw[n] = sum_d bq[d] * wtb[n*1024+d], n = blk*4+wave
// blocks [256,512): k_sk body, s = blk-256: bx=s>>5, by=(s>>2)&7, bz=s&3
__global__ __launch_bounds__(256)
void k_mid(const float* __restrict__ bq, const bf16_t* __restrict__ wtb,
           const bf16_t* __restrict__ wqt, float* __restrict__ bqwO,
           float* __restrict__ oAt)
{
    __shared__ __align__(16) bf16_t As[128 * 32];
    __shared__ __align__(16) bf16_t Bs[128 * 32];

    const int tid  = threadIdx.x;
    const int wave = tid >> 6;
    const int lane = tid & 63;

    if (blockIdx.x < 256) {
        const int n = blockIdx.x * 4 + wave;
        const bf16_t* row = wtb + (long)n * 1024;
        float s = 0.f;
#pragma unroll
        for (int c = 0; c < 2; ++c) {
            const int d0 = (lane + c * 64) * 8;
            const bf16x8 v = *reinterpret_cast<const bf16x8*>(row + d0);
#pragma unroll
            for (int e = 0; e < 8; ++e) s += bq[d0 + e] * (float)v[e];
        }
#pragma unroll
        for (int off = 32; off; off >>= 1) s += __shfl_down(s, off);
        if (lane == 0) bqwO[n] = s;
        return;
    }

    const int s  = blockIdx.x - 256;
    const int bm = (s >> 5) * 128;
    const int bn = ((s >> 2) & 7) * 128;
    const int kb = (s & 3) * 256;
    const int wr = wave >> 1, wc = wave & 1;
    const int lhi = lane >> 4, llo = lane & 15;

    f32x4 acc[4][4];
    const f32x4 fz = {0.f, 0.f, 0.f, 0.f};
#pragma unroll
    for (int i = 0; i < 4; ++i)
#pragma unroll
        for (int j = 0; j < 4; ++j) acc[i][j] = fz;

    for (int k0 = 0; k0 < 256; k0 += 32) {
#pragma unroll
        for (int i = 0; i < 2; ++i) {
            const int c  = wave * 128 + i * 64 + lane;
            const int r  = c >> 2;
            const int cc = (c & 3) << 3;
            const long ga = (long)(bm + r) * 1024 + kb + k0 + cc;
            const long gb = (long)(bn + r) * 1024 + kb + k0 + cc;
            const int lbase = (wave * 128 + i * 64) << 3;
            __builtin_amdgcn_global_load_lds(
                (const __attribute__((address_space(1))) uint32_t*)(wtb + ga),
                (__attribute__((address_space(3))) uint32_t*)(&As[lbase]), 16, 0, 0);
            __builtin_amdgcn_global_load_lds(
                (const __attribute__((address_space(1))) uint32_t*)(wqt + gb),
                (__attribute__((address_space(3))) uint32_t*)(&Bs[lbase]), 16, 0, 0);
        }
        __syncthreads();

        bf16x8 af[4], bfr[4];
#pragma unroll
        for (int mi = 0; mi < 4; ++mi)
            af[mi] = *reinterpret_cast<const bf16x8*>(&As[(wr * 64 + mi * 16 + llo) * 32 + lhi * 8]);
#pragma unroll
        for (int ni = 0; ni < 4; ++ni)
            bfr[ni] = *reinterpret_cast<const bf16x8*>(&Bs[(wc * 64 + ni * 16 + llo) * 32 + lhi * 8]);
#pragma unroll
        for (int mi = 0; mi < 4; ++mi)
#pragma unroll
            for (int ni = 0; ni < 4; ++ni)
                acc[mi][ni] = __builtin_amdgcn_mfma_f32_16x16x32_bf16(af[mi], bfr[ni], acc[mi][ni], 0, 0, 0);
        __syncthreads();
    }

#pragma unroll
    for (int mi = 0; mi < 4; ++mi) {
        const int r0 = bm + wr * 64 + mi * 16 + lhi * 4;
#pragma unroll
        for (int ni = 0; ni < 4; ++ni) {
            const int cg = bn + wc * 64 + ni * 16 + llo;
            const f32x4 v = acc[mi][ni];
#pragma unroll
            for (int j = 0; j < 4; ++j)
                atomicAdd(&oAt[(long)(r0 + j) * 1024 + cg], v[j]);
        }
    }
}

// ========== BM=128 x BN_, BK=64, double-buffered, swizzled LDS (R8-proven) ==========
// C[m][n] = sum_k A[m][k] * B[n][k], K=1024 (16 tiles of BK=64).
// 8 waves (2M x 4N): per-wave 64 x BN_/4. LDS: 2 x (128+BN_)*128B (80/64 KB)
// -> 2 blocks/CU. Sync per tile: { stage(t+1); vmcnt(LPT) [t landed, t+1 in
// flight]; barrier; reads+MFMA (2 k-halves); lgkmcnt(0); barrier }.
// Swizzle: rows are 128B (8 x 16B chunks); phys chunk = logical ^ (row & 7)
// (involution; staged linearly from inverse-swizzled global source).
// MODE 1 (BN_=192): qkv projection epilogue (q/k/v routing + bias), grid 64x16.
// MODE 2 (BN_=128): oF[z + m*1024+n] += SCALE*acc, flat grid 512, XCD = batch.
template<int BN_, int MODE>
__global__ __launch_bounds__(512, 2)
void k_db(const bf16_t* __restrict__ A, const bf16_t* __restrict__ Bp,
          const float* __restrict__ bqw, const float* __restrict__ bqkv,
          bf16_t* __restrict__ oQW, bf16_t* __restrict__ oK, float* __restrict__ oF)
{
    constexpr int NF   = BN_ / 64;          // n-frags per wave: 3 or 2
    constexpr int LB   = BN_ / 64;          // B loads/thread: 3 or 2
    constexpr int LPT  = 2 + LB;            // loads/thread/tile
    constexpr int SLOT = (128 + BN_) * 128; // bytes per buffer
    constexpr int NTT  = 16;                // K / 64
    __shared__ __align__(16) unsigned char slds[2 * SLOT];

    const int tid  = threadIdx.x;
    const int wave = tid >> 6, lane = tid & 63;
    const int wm = wave >> 2, wn = wave & 3;
    const int llo = lane & 15, lhi = lane >> 4;

    int bm, bn; long zz = 0;
    if (MODE == 1) {
        bm = blockIdx.x * 128; bn = blockIdx.y * BN_;
    } else {
        const int nw = ((int)blockIdx.x & 7) * 64 + ((int)blockIdx.x >> 3);
        zz = (long)(nw >> 6) << 20;         // batch = XCD id (L2-resident qw/k)
        const int r = nw & 63;
        bm = (r >> 3) * 128; bn = (r & 7) * 128;
    }

    // per-thread inverse-swizzled staging sources + linear LDS dests
    const bf16_t* sp[LPT]; int dst[LPT];
#pragma unroll
    for (int j = 0; j < 2; ++j) {
        const int C = j * 512 + tid;        // A chunk id, 0..1023
        const int r = C >> 3, u = (C & 7) ^ (r & 7);
        sp[j] = A + zz + (long)(bm + r) * 1024 + (u << 3);
        dst[j] = C << 4;
    }
#pragma unroll
    for (int j = 0; j < LB; ++j) {
        const int C = j * 512 + tid;        // B chunk id, 0..BN_*8-1
        const int r = C >> 3, u = (C & 7) ^ (r & 7);
        sp[2 + j] = Bp + zz + (long)(bn + r) * 1024 + (u << 3);
        dst[2 + j] = 16384 + (C << 4);
    }

    auto stage = [&](int tt) {
        unsigned char* s = &slds[(tt & 1) * SLOT];
        const long ko = (long)tt << 6;
#pragma unroll
        for (int j = 0; j < LPT; ++j)
            __builtin_amdgcn_global_load_lds(
                (const __attribute__((address_space(1))) uint32_t*)(sp[j] + ko),
                (__attribute__((address_space(3))) uint32_t*)(s + dst[j]), 16, 0, 0);
    };

    f32x4 acc[4][NF];
    const f32x4 fz = {0.f, 0.f, 0.f, 0.f};
#pragma unroll
    for (int i = 0; i < 4; ++i)
#pragma unroll
        for (int j = 0; j < NF; ++j) acc[i][j] = fz;

    stage(0);

    for (int t = 0; t < NTT; ++t) {
        if (t + 1 < NTT) {
            stage(t + 1);
            asm volatile("s_waitcnt vmcnt(%0)" :: "i"(LPT) : "memory");
        } else {
            asm volatile("s_waitcnt vmcnt(0)" ::: "memory");
        }
        __builtin_amdgcn_s_barrier();

        const unsigned char* sb = &slds[(t & 1) * SLOT];
#pragma unroll
        for (int ks = 0; ks < 2; ++ks) {
            bf16x8 af[4], bfv[NF];
#pragma unroll
            for (int mi = 0; mi < 4; ++mi) {
                const int r = wm * 64 + mi * 16 + llo;
                af[mi] = *reinterpret_cast<const bf16x8*>(
                    sb + r * 128 + ((((ks << 2) | lhi) ^ (r & 7)) << 4));
            }
#pragma unroll
            for (int ni = 0; ni < NF; ++ni) {
                const int r = wn * (NF * 16) + ni * 16 + llo;
                bfv[ni] = *reinterpret_cast<const bf16x8*>(
                    sb + 16384 + r * 128 + ((((ks << 2) | lhi) ^ (r & 7)) << 4));
            }
            __builtin_amdgcn_s_setprio(1);
#pragma unroll
            for (int mi = 0; mi < 4; ++mi)
#pragma unroll
                for (int ni = 0; ni < NF; ++ni)
                    acc[mi][ni] = __builtin_amdgcn_mfma_f32_16x16x32_bf16(
                        af[mi], bfv[ni], acc[mi][ni], 0, 0, 0);
            __builtin_amdgcn_s_setprio(0);
        }
        // all LDS reads of this buffer retired before it can be restaged
        asm volatile("s_waitcnt lgkmcnt(0)" ::: "memory");
        __builtin_amdgcn_s_barrier();
    }

    // ---------------- epilogue ----------------
#pragma unroll
    for (int mi = 0; mi < 4; ++mi) {
        const long r0 = bm + wm * 64 + mi * 16 + lhi * 4;
#pragma unroll
        for (int ni = 0; ni < NF; ++ni) {
            const int cg = bn + wn * (NF * 16) + ni * 16 + llo;
            const f32x4 v = acc[mi][ni];
            if (MODE == 1) {
                const int sec = cg >> 10;
                const int c1  = cg & 1023;
                const float bb = (sec == 0) ? bqw[cg] : bqkv[cg];
#pragma unroll
                for (int j = 0; j < 4; ++j) {
                    const long idx = (r0 + j) * 1024 + c1;
                    const float val = v[j] + bb;
                    if (sec == 0)      oQW[idx] = (bf16_t)val;
                    else if (sec == 1) oK[idx] = (bf16_t)val;
                    else               oF[idx] = val;
                }
            } else {
#pragma unroll
                for (int j = 0; j < 4; ++j) {
                    const long idx = zz + (r0 + j) * 1024 + cg;
                    oF[idx] = oF[idx] + SCALE * v[j];
                }
            }
        }
    }
}

extern "C" void kernel_launch(void* const* d_in, const int* in_sizes, int n_in,
                              void* d_out, int out_size, void* d_ws, size_t ws_size,
                              hipStream_t stream) {
    const float* x    = (const float*)d_in[0];
    const float* Wqkv = (const float*)d_in[1];
    const float* bqkv = (const float*)d_in[2];
    const float* w    = (const float*)d_in[3];
    float* out = (float*)d_out;

    // workspace layout (54 MiB + 64 KiB)
    char* ws = (char*)d_ws;
    bf16_t* xb   = (bf16_t*)(ws);                          // 16 MiB
    bf16_t* wbig = (bf16_t*)(ws + (16l << 20));            // 6 MiB: [B'; Wk; Wv]
    float*  bqw  = (float*) (ws + (22l << 20));            // 4 KiB (64 KiB reserved)
    bf16_t* kb   = (bf16_t*)(ws + (22l << 20) + 65536);    // 16 MiB
    bf16_t* qwb  = (bf16_t*)(ws + (38l << 20) + 65536);    // 16 MiB (region reused)
    bf16_t* wtb  = qwb;                    // 2 MiB WeffT   (dead before qwb written)
    bf16_t* wqt  = qwb + 1048576;          // 2 MiB WqT     (dead before qwb written)
    float*  bp32 = (float*)(qwb + 2097152);// 4 MiB f32 B'  (dead before qwb written)
    if (ws_size < (size_t)(54l << 20) + 65536) return;

    // K1: fused preamble (x-cvt | Wkv-cvt | WeffT | WqT | bp32-zero)
    k_prep<<<13312, 256, 0, stream>>>(x, Wqkv, w, xb, wbig, wtb, wqt, bp32);

    // K2: bqw dot + B' split-K GEMM (atomicAdd into bp32)
    k_mid<<<512, 256, 0, stream>>>(bqkv, wtb, wqt, bqw, bp32);

    // K3: B' f32 -> bf16 into wbig rows [0,1024)
    k_cvt<<<1024, 256, 0, stream>>>(bp32, wbig, 262144);

    // fused projection: [qw | k | v] = x @ wbig^T + bias; 1024 blocks = 2 exact rounds
    k_db<192, 1><<<dim3(64, 16), 512, 0, stream>>>(xb, wbig, bqw, bqkv, qwb, kb, out);

    // scores: out += SCALE * qw @ k^T; 512 blocks = 1 round, XCD = batch
    k_db<128, 2><<<dim3(512), 512, 0, stream>>>(qwb, kb, nullptr, nullptr,
                                                nullptr, nullptr, out);
}